// Round 3
// baseline (156.261 us; speedup 1.0000x reference)
//
#include <hip/hip_runtime.h>
#include <float.h>

#define B 16
#define BH 8           // batches per phase: working set = BH*16MiB + tiles << 256MiB L3
#define H 256
#define W 256
#define C 64
#define TH 16
#define TW 16
#define NTH (H / TH)   // 16 h-tiles
#define NTW (W / TW)   // 16 w-tiles

// ---------------------------------------------------------------------------
// k_tilemax: one pass over a BH-batch slice of the input.
//   hTile[b][t][w][c] = max over h in tile t of in[b,h,w,c]
//   wTile[b][h][s][c] = max over w in tile s of in[b,h,w,c]
// grid = BH*NTH*(W/64) blocks, 256 threads. b is slice-local (pointer offset).
// All loads/stores: lane=c -> 256B coalesced. Input reads NORMAL (want the
// slice resident in L3 for k_final's re-read); tile writes NORMAL (re-read
// by scan + final).
// ---------------------------------------------------------------------------
__global__ __launch_bounds__(256) void k_tilemax(const float* __restrict__ in,
                                                 float* __restrict__ hTile,
                                                 float* __restrict__ wTile)
{
    int blk = blockIdx.x;
    int wq = blk & 3;                 // which 64-wide w chunk
    int t  = (blk >> 2) & (NTH - 1);  // h-tile
    int b  = blk >> 6;                // slice-local batch
    int tid = threadIdx.x;
    int c  = tid & 63;
    int wg = tid >> 6;                // 0..3
    int wbase = wq * 64 + wg * 16;
    int s = wbase / TW;               // w-tile index

    float hrun[16];
#pragma unroll
    for (int j = 0; j < 16; ++j) hrun[j] = -FLT_MAX;

    int h0 = t * TH;
    for (int hh = 0; hh < TH; ++hh) {
        int h = h0 + hh;
        const float* row = in + ((size_t)(b * H + h) * W + wbase) * C + c;
        float wmax = -FLT_MAX;
#pragma unroll
        for (int j = 0; j < 16; ++j) {
            float v = row[j * C];
            hrun[j] = fmaxf(hrun[j], v);
            wmax = fmaxf(wmax, v);
        }
        wTile[((size_t)(b * H + h) * NTW + s) * C + c] = wmax;
    }
    float* hout = hTile + ((size_t)(b * NTH + t) * W + wbase) * C + c;
#pragma unroll
    for (int j = 0; j < 16; ++j) hout[j * C] = hrun[j];
}

// ---------------------------------------------------------------------------
// k_sufscan2: both in-place EXCLUSIVE suffix-max scans in ONE dispatch.
//   hTile: [BH][16][W*C]  inner = 2^14, columns hcols = BH*W*C
//   wTile: [BH*H][16][C]  inner = 2^6,  columns BH*H*C (== hcols)
// grid = 2*hcols/256 blocks; first half -> hTile, rest -> wTile.
// ---------------------------------------------------------------------------
__global__ __launch_bounds__(256) void k_sufscan2(float* __restrict__ hT,
                                                  float* __restrict__ wT,
                                                  int hcols)
{
    int idx = blockIdx.x * 256 + threadIdx.x;
    float* buf;
    int shift;
    if (idx < hcols) {                // block-uniform branch (hcols % 256 == 0)
        buf = hT;  shift = 14;
    } else {
        buf = wT;  shift = 6;  idx -= hcols;
    }
    int inner = 1 << shift;
    int o = idx >> shift;
    int i = idx & (inner - 1);
    float* p = buf + ((size_t)o * 16) * inner + i;
    float v[16];
#pragma unroll
    for (int tt = 0; tt < 16; ++tt) v[tt] = p[tt * inner];
    float run = -FLT_MAX;
#pragma unroll
    for (int tt = 15; tt >= 0; --tt) {
        float nv = v[tt];
        v[tt] = run;              // exclusive: max over strictly-later tiles
        run = fmaxf(run, nv);
    }
#pragma unroll
    for (int tt = 0; tt < 16; ++tt) p[tt * inner] = v[tt];
}

// ---------------------------------------------------------------------------
// k_final: out = max(local h-suffix, hSuf) + max(local w-suffix, wSuf)
// Operates on the same BH-batch slice; input re-read should be ~fully
// L3-resident (slice = 128 MiB + 16 MiB tiles < 256 MiB Infinity Cache).
// Output stores NON-TEMPORAL so the write stream doesn't evict the input.
// ---------------------------------------------------------------------------
__global__ __launch_bounds__(256) void k_final(const float* __restrict__ in,
                                               const float* __restrict__ hSuf,
                                               const float* __restrict__ wSuf,
                                               float* __restrict__ out)
{
    int blk = (gridDim.x - 1) - blockIdx.x;   // reversed (harmless; tail reuse)
    int wq = blk & 3;
    int t  = (blk >> 2) & (NTH - 1);
    int b  = blk >> 6;
    int tid = threadIdx.x;
    int c  = tid & 63;
    int wg = tid >> 6;
    int wbase = wq * 64 + wg * 16;
    int s = wbase / TW;

    float hrun[16];
    const float* hs = hSuf + ((size_t)(b * NTH + t) * W + wbase) * C + c;
#pragma unroll
    for (int j = 0; j < 16; ++j) hrun[j] = __builtin_nontemporal_load(&hs[j * C]);

    int h0 = t * TH;
    for (int hh = TH - 1; hh >= 0; --hh) {
        int h = h0 + hh;
        const float* row = in + ((size_t)(b * H + h) * W + wbase) * C + c;
        float v[16];
#pragma unroll
        for (int j = 0; j < 16; ++j) {
            v[j] = row[j * C];                 // NORMAL load: want L3 hits
            hrun[j] = fmaxf(hrun[j], v[j]);
        }
        float ws = __builtin_nontemporal_load(
            &wSuf[((size_t)(b * H + h) * NTW + s) * C + c]);
        float* orow = out + ((size_t)(b * H + h) * W + wbase) * C + c;
#pragma unroll
        for (int j = 15; j >= 0; --j) {
            ws = fmaxf(ws, v[j]);
            __builtin_nontemporal_store(hrun[j] + ws, &orow[j * C]);
        }
    }
}

// ---------------------------------------------------------------------------
// Fallback (no workspace): two serial-scan kernels, fully coalesced.
// ---------------------------------------------------------------------------
__global__ __launch_bounds__(256) void k_wscan(const float* __restrict__ in,
                                               float* __restrict__ out)
{
    int idx = blockIdx.x * 256 + threadIdx.x;   // (b*H + h)*C + c
    int c  = idx & 63;
    int bh = idx >> 6;
    const float* p = in + (size_t)bh * W * C + c;
    float* q = out + (size_t)bh * W * C + c;
    float run = -FLT_MAX;
    for (int w = W - 1; w >= 0; --w) {
        run = fmaxf(run, p[w * C]);
        q[w * C] = run;
    }
}

__global__ __launch_bounds__(256) void k_hscan_add(const float* __restrict__ in,
                                                   float* __restrict__ out)
{
    int idx = blockIdx.x * 256 + threadIdx.x;   // b*(W*C) + w*C + c
    int wc = idx & (W * C - 1);
    int b  = idx >> 14;                          // W*C = 16384 = 2^14
    const float* p = in + (size_t)b * H * W * C + wc;
    float* q = out + (size_t)b * H * W * C + wc;
    float run = -FLT_MAX;
    for (int h = H - 1; h >= 0; --h) {
        run = fmaxf(run, p[(size_t)h * W * C]);
        q[(size_t)h * W * C] += run;
    }
}

extern "C" void kernel_launch(void* const* d_in, const int* in_sizes, int n_in,
                              void* d_out, int out_size, void* d_ws, size_t ws_size,
                              hipStream_t stream)
{
    const float* in = (const float*)d_in[0];
    float* out = (float*)d_out;

    const size_t sliceElems = (size_t)BH * H * W * C;       // per-phase input elems
    const size_t tileElems  = (size_t)BH * NTH * W * C;     // 2,097,152 (= BH*H*NTW*C)
    const size_t need = 2 * tileElems * sizeof(float);      // 16 MiB

    if (ws_size >= need) {
        float* hTile = (float*)d_ws;
        float* wTile = hTile + tileElems;
        const int hcols = BH * W * C;                        // 131072

        for (int phase = 0; phase < B / BH; ++phase) {
            const float* inS = in + (size_t)phase * sliceElems;
            float* outS = out + (size_t)phase * sliceElems;
            k_tilemax<<<BH * NTH * (W / 64), 256, 0, stream>>>(inS, hTile, wTile);
            k_sufscan2<<<2 * hcols / 256, 256, 0, stream>>>(hTile, wTile, hcols);
            k_final<<<BH * NTH * (W / 64), 256, 0, stream>>>(inS, hTile, wTile, outS);
        }
    } else {
        k_wscan<<<B * H * C / 256, 256, 0, stream>>>(in, out);
        k_hscan_add<<<B * W * C / 256, 256, 0, stream>>>(in, out);
    }
}